// Round 2
// baseline (87.494 us; speedup 1.0000x reference)
//
#include <hip/hip_runtime.h>

// Voxel merge (2x2x2, blocks ordered i*4+j*2+k) + mask + LayerNorm(768) + GEMM [65536,768]x[768,192].
// B=2, D=H=W=64, C=96 -> merged M=65536 rows of 768 ch; out 192 ch + mask_out.
#define C8   768
#define NOUT 192
#define M_TOTAL 65536
#define OUT0 (M_TOTAL * NOUT)   // 12582912; mask_out follows
#define CLDS_STRIDE 196         // padded f32 row stride -> <=2-way LDS conflicts

typedef __attribute__((ext_vector_type(8))) short  short8;   // 8 x bf16 MFMA fragment
typedef __attribute__((ext_vector_type(4))) float  f32x4;    // MFMA accumulator
typedef __attribute__((ext_vector_type(4))) unsigned short us4;

__device__ __forceinline__ unsigned short f2bf(float f) {
    union { float f; unsigned u; } a; a.f = f;
    unsigned r = a.u + 0x7FFFu + ((a.u >> 16) & 1u);  // round-to-nearest-even
    return (unsigned short)(r >> 16);
}

// Pre-pack W [768][192] fp32 -> bf16 in per-lane MFMA B-fragment order:
// Wb[((ks*12 + fn)*64 + l)*8 + e] = bf16(W[(ks*32 + (l>>4)*8 + e)*192 + fn*16 + (l&15)])
__global__ __launch_bounds__(256) void prepw_kernel(const float* __restrict__ Wm,
                                                    unsigned short* __restrict__ Wb) {
    int t = blockIdx.x * 256 + threadIdx.x;
    if (t >= 24 * 12 * 512) return;
    int e  = t & 7;
    int l  = (t >> 3) & 63;
    int f  = t >> 9;          // ks*12 + fn
    int fn = f % 12;
    int ks = f / 12;
    int k = ks * 32 + ((l >> 4) << 3) + e;
    int n = fn * 16 + (l & 15);
    Wb[t] = f2bf(Wm[k * NOUT + n]);
}

__global__ __launch_bounds__(512, 6) void fused_kernel(
    const float* __restrict__ x, const float* __restrict__ mask,
    const float* __restrict__ gamma, const float* __restrict__ beta,
    const unsigned short* __restrict__ Wb, float* __restrict__ out)
{
    // LDS: phase 1/2 view = A tile 32x768 bf16 (stride 1536B, XOR-swizzled by (row&7)<<4);
    //      phase 3 view = C tile 32 x 192 f32 (stride 196 floats). Aliased (barrier-separated).
    __shared__ __align__(16) char smem[49152];
    unsigned short* Alds = (unsigned short*)smem;
    float*          Clds = (float*)smem;

    const int tid = threadIdx.x;
    const int l   = tid & 63;
    const int wv  = tid >> 6;        // 0..7
    const int rowbase = blockIdx.x * 32;

    // ---------------- Phase 1: gather + mask + LayerNorm -> LDS bf16 ----------------
#pragma unroll 2
    for (int i = 0; i < 4; ++i) {
        const int r  = (wv << 2) + i;          // each wave owns 4 rows
        const int rg = rowbase + r;
        const int w2 = rg & 31, h2 = (rg >> 5) & 31, d2 = (rg >> 10) & 31, b = rg >> 15;
        const int vbase = ((b * 64 + d2 * 2) * 64 + h2 * 2) * 64 + w2 * 2; // mask-space idx

        float vs[12];
        float s = 0.f, s2 = 0.f;
#pragma unroll
        for (int m = 0; m < 3; ++m) {
            const int c8 = (m << 8) + (l << 2);          // merged channel (x4)
            const int bi = c8 / 96;                      // sub-voxel block (i*4+j*2+k)
            const int ch = c8 - bi * 96;
            const int voff = vbase + ((bi >> 2) * 64 + ((bi >> 1) & 1)) * 64 + (bi & 1);
            const float4 v = *(const float4*)(x + (size_t)voff * 96 + ch);
            const float mv = mask[voff];
            const float a0 = v.x * mv, a1 = v.y * mv, a2 = v.z * mv, a3 = v.w * mv;
            vs[m * 4 + 0] = a0; vs[m * 4 + 1] = a1; vs[m * 4 + 2] = a2; vs[m * 4 + 3] = a3;
            s  += (a0 + a1) + (a2 + a3);
            s2 += (a0 * a0 + a1 * a1) + (a2 * a2 + a3 * a3);
        }
#pragma unroll
        for (int off = 32; off >= 1; off >>= 1) {   // 64-lane butterfly reduce
            s  += __shfl_xor(s,  off);
            s2 += __shfl_xor(s2, off);
        }
        const float mu  = s * (1.f / 768.f);
        const float var = s2 * (1.f / 768.f) - mu * mu;   // biased variance
        const float rs  = rsqrtf(var + 1e-5f);
        const int swz = (r & 7) << 4;
        char* rowp = (char*)Alds + r * 1536;
#pragma unroll
        for (int m = 0; m < 3; ++m) {
            const int c8 = (m << 8) + (l << 2);
            const float4 g  = *(const float4*)(gamma + c8);
            const float4 bt = *(const float4*)(beta  + c8);
            us4 o;
            o.x = f2bf((vs[m * 4 + 0] - mu) * rs * g.x + bt.x);
            o.y = f2bf((vs[m * 4 + 1] - mu) * rs * g.y + bt.y);
            o.z = f2bf((vs[m * 4 + 2] - mu) * rs * g.z + bt.z);
            o.w = f2bf((vs[m * 4 + 3] - mu) * rs * g.w + bt.w);
            *(us4*)(rowp + ((c8 << 1) ^ swz)) = o;   // 8B store, wave-linear -> no conflict
        }
        if (l == 0) {   // mask_out = (sum of 8 merged mask vals) > 0
            float ms = 0.f;
#pragma unroll
            for (int bi = 0; bi < 8; ++bi)
                ms += mask[vbase + ((bi >> 2) * 64 + ((bi >> 1) & 1)) * 64 + (bi & 1)];
            out[OUT0 + rg] = (ms > 0.f) ? 1.0f : 0.0f;
        }
    }
    __syncthreads();

    // ------- Phase 2: [32 x 192] = A[32x768] * W[768x192] via MFMA, (K-half, col-group) split -------
    const int cg = wv & 3;     // col group: 48 cols = 3 fragments
    const int kh = wv >> 2;    // K half: 12 of 24 K-steps
    f32x4 acc[2][3] = {};
    const int lrow = l & 15;
    const int kq   = (l >> 4) << 4;        // byte offset of this lane's k-chunk
    const int swz2 = (l & 7) << 4;         // matches (row&7)<<4 for rows lrow and lrow+16
    const char* aBase = (const char*)Alds + lrow * 1536;
    const short8* Wv = (const short8*)Wb;
    const int bbase = cg * 192 + l;

#pragma unroll 2
    for (int ks = kh * 12; ks < kh * 12 + 12; ++ks) {
        const int ko = ((ks << 6) + kq) ^ swz2;
        short8 a0 = *(const short8*)(aBase + ko);
        short8 a1 = *(const short8*)(aBase + 16 * 1536 + ko);
        short8 b0 = Wv[ks * 768 + bbase];
        short8 b1 = Wv[ks * 768 + bbase + 64];
        short8 b2 = Wv[ks * 768 + bbase + 128];
        acc[0][0] = __builtin_amdgcn_mfma_f32_16x16x32_bf16(a0, b0, acc[0][0], 0, 0, 0);
        acc[1][0] = __builtin_amdgcn_mfma_f32_16x16x32_bf16(a1, b0, acc[1][0], 0, 0, 0);
        acc[0][1] = __builtin_amdgcn_mfma_f32_16x16x32_bf16(a0, b1, acc[0][1], 0, 0, 0);
        acc[1][1] = __builtin_amdgcn_mfma_f32_16x16x32_bf16(a1, b1, acc[1][1], 0, 0, 0);
        acc[0][2] = __builtin_amdgcn_mfma_f32_16x16x32_bf16(a0, b2, acc[0][2], 0, 0, 0);
        acc[1][2] = __builtin_amdgcn_mfma_f32_16x16x32_bf16(a1, b2, acc[1][2], 0, 0, 0);
    }

    // C/D layout: col = lane&15, row = (lane>>4)*4 + j  (m89-verified)
    __syncthreads();   // all A-reads done; smem becomes the C tile
    if (kh == 1) {     // write partial
#pragma unroll
        for (int fm = 0; fm < 2; ++fm)
#pragma unroll
            for (int fn = 0; fn < 3; ++fn)
#pragma unroll
                for (int j = 0; j < 4; ++j) {
                    const int row = fm * 16 + ((l >> 4) << 2) + j;
                    const int col = cg * 48 + fn * 16 + lrow;
                    Clds[row * CLDS_STRIDE + col] = acc[fm][fn][j];
                }
    }
    __syncthreads();
    if (kh == 0) {     // add own partial
#pragma unroll
        for (int fm = 0; fm < 2; ++fm)
#pragma unroll
            for (int fn = 0; fn < 3; ++fn)
#pragma unroll
                for (int j = 0; j < 4; ++j) {
                    const int row = fm * 16 + ((l >> 4) << 2) + j;
                    const int col = cg * 48 + fn * 16 + lrow;
                    Clds[row * CLDS_STRIDE + col] += acc[fm][fn][j];
                }
    }
    __syncthreads();
    // ---------------- Phase 3: cooperative fully-coalesced float4 store ----------------
#pragma unroll
    for (int idx = tid; idx < 32 * 48; idx += 512) {
        const int row = idx / 48, c4 = idx % 48;
        const float4 v = *(const float4*)&Clds[row * CLDS_STRIDE + c4 * 4];
        *(float4*)&out[(size_t)(rowbase + row) * NOUT + c4 * 4] = v;
    }
}

extern "C" void kernel_launch(void* const* d_in, const int* in_sizes, int n_in,
                              void* d_out, int out_size, void* d_ws, size_t ws_size,
                              hipStream_t stream) {
    const float* x     = (const float*)d_in[0];
    const float* mask  = (const float*)d_in[1];
    const float* gamma = (const float*)d_in[2];
    const float* beta  = (const float*)d_in[3];
    const float* Wm    = (const float*)d_in[4];
    float* out = (float*)d_out;
    unsigned short* Wb = (unsigned short*)d_ws;   // 294912 B of scratch

    prepw_kernel<<<576, 256, 0, stream>>>(Wm, Wb);
    fused_kernel<<<2048, 512, 0, stream>>>(x, mask, gamma, beta, Wb, out);
}